// Round 7
// baseline (37.918 us; speedup 1.0000x reference)
//
#include <hip/hip_runtime.h>
#include <math.h>

#define EPS_F 1e-10f

typedef __attribute__((ext_vector_type(4))) float f4;
typedef __attribute__((ext_vector_type(4))) unsigned int u4;
typedef __attribute__((ext_vector_type(2))) float f2;

__device__ __forceinline__ f4 v_fabs(f4 x) {
  u4 u = __builtin_bit_cast(u4, x);
  u &= 0x7fffffffu;
  return __builtin_bit_cast(f4, u);
}
__device__ __forceinline__ f4 v_max(f4 a, f4 b) { return __builtin_elementwise_max(a, b); }
__device__ __forceinline__ f4 v_min(f4 a, f4 b) { return __builtin_elementwise_min(a, b); }
__device__ __forceinline__ f4 v_log(f4 x) {
  f4 r; r.x = __logf(x.x); r.y = __logf(x.y); r.z = __logf(x.z); r.w = __logf(x.w); return r;
}
__device__ __forceinline__ f4 v_rcp(f4 x) {
  f4 r;
  r.x = __builtin_amdgcn_rcpf(x.x); r.y = __builtin_amdgcn_rcpf(x.y);
  r.z = __builtin_amdgcn_rcpf(x.z); r.w = __builtin_amdgcn_rcpf(x.w);
  return r;
}
__device__ __forceinline__ f4 v_rsq(f4 x) {
  f4 r;
  r.x = __builtin_amdgcn_rsqf(x.x); r.y = __builtin_amdgcn_rsqf(x.y);
  r.z = __builtin_amdgcn_rsqf(x.z); r.w = __builtin_amdgcn_rsqf(x.w);
  return r;
}
__device__ __forceinline__ f4 v_sqrt(f4 x) {
  f4 r;
  r.x = __builtin_amdgcn_sqrtf(x.x); r.y = __builtin_amdgcn_sqrtf(x.y);
  r.z = __builtin_amdgcn_sqrtf(x.z); r.w = __builtin_amdgcn_sqrtf(x.w);
  return r;
}
__device__ __forceinline__ f4 v_cos(f4 x) {
  f4 r; r.x = __cosf(x.x); r.y = __cosf(x.y); r.z = __cosf(x.z); r.w = __cosf(x.w); return r;
}

// acos via minimax poly (|err| ~ 2e-8 rad)
__device__ __forceinline__ f4 v_acos(f4 r) {
  const f4 t = v_fabs(r);
  const f4 s = v_sqrt(1.0f - t);
  f4 p = f4{-0.0012624911f, -0.0012624911f, -0.0012624911f, -0.0012624911f};
  p = p * t +  0.0066700901f;
  p = p * t + -0.0170881256f;
  p = p * t +  0.0308918810f;
  p = p * t + -0.0501743046f;
  p = p * t +  0.0889789874f;
  p = p * t + -0.2145988016f;
  p = p * t +  1.5707963050f;
  const f4 ac = s * p;                         // acos(|r|)
  f4 res;
  res.x = (r.x < 0.0f) ? (3.14159265358979f - ac.x) : ac.x;
  res.y = (r.y < 0.0f) ? (3.14159265358979f - ac.y) : ac.y;
  res.z = (r.z < 0.0f) ? (3.14159265358979f - ac.z) : ac.z;
  res.w = (r.w < 0.0f) ? (3.14159265358979f - ac.w) : ac.w;
  return res;
}

// Fused ||logm(D1)-logm(D2)||_F^2 for TWO matrix pairs in lockstep:
// lanes = {D1_pairA, D2_pairA, D1_pairB, D2_pairB}. Returns {lossA, lossB}.
__device__ __forceinline__ f2 pair_loss(f4 a00, f4 a01, f4 a02,
                                        f4 a11, f4 a12, f4 a22) {
  a00 = v_fabs(a00); a01 = v_fabs(a01); a02 = v_fabs(a02);
  a11 = v_fabs(a11); a12 = v_fabs(a12); a22 = v_fabs(a22);

  const f4 q   = (a00 + a11 + a22) * (1.0f / 3.0f);
  const f4 b00 = a00 - q, b11 = a11 - q, b22 = a22 - q;
  const f4 p2  = b00 * b00 + b11 * b11 + b22 * b22 +
                 2.0f * (a01 * a01 + a02 * a02 + a12 * a12);

  // p2c = max(p2/6, floor) keeps p>0 so downstream denominators stay normal
  const f4 p2c  = v_max(p2 * (1.0f / 6.0f), 1e-10f * q * q + 1e-35f);
  const f4 pinv = v_rsq(p2c);          // 1/p
  const f4 p    = p2c * pinv;          // sqrt(p2c)

  const f4 detB = b00 * (b11 * b22 - a12 * a12)
                - a01 * (a01 * b22 - a12 * a02)
                + a02 * (a01 * a12 - b11 * a02);
  f4 r = detB * 0.5f * pinv * pinv * pinv;
  r = v_min(f4{1.0f, 1.0f, 1.0f, 1.0f}, v_max(f4{-1.0f, -1.0f, -1.0f, -1.0f}, r));
  const f4 phi  = v_acos(r) * (1.0f / 3.0f);
  const f4 twop = 2.0f * p;
  const f4 l1 = q + twop * v_cos(phi);                          // largest
  const f4 l3 = q + twop * v_cos(phi + 2.0943951023931953f);    // smallest
  const f4 l2 = 3.0f * q - l1 - l3;

  // A^2 (symmetric, unique entries)
  const f4 s00 = a00 * a00 + a01 * a01 + a02 * a02;
  const f4 s01 = a00 * a01 + a01 * a11 + a02 * a12;
  const f4 s02 = a00 * a02 + a01 * a12 + a02 * a22;
  const f4 s11 = a01 * a01 + a11 * a11 + a12 * a12;
  const f4 s12 = a01 * a02 + a11 * a12 + a12 * a22;
  const f4 s22 = a02 * a02 + a12 * a12 + a22 * a22;

  // isolated extreme eigenvalue = alpha; beta = middle; gamma = other extreme
  const f4 g12 = l1 - l2, g23 = l2 - l3;
  f4 alpha, gamma;
  alpha.x = (g12.x >= g23.x) ? l1.x : l3.x;  gamma.x = (g12.x >= g23.x) ? l3.x : l1.x;
  alpha.y = (g12.y >= g23.y) ? l1.y : l3.y;  gamma.y = (g12.y >= g23.y) ? l3.y : l1.y;
  alpha.z = (g12.z >= g23.z) ? l1.z : l3.z;  gamma.z = (g12.z >= g23.z) ? l3.z : l1.z;
  alpha.w = (g12.w >= g23.w) ? l1.w : l3.w;  gamma.w = (g12.w >= g23.w) ? l3.w : l1.w;
  const f4 beta = l2;

  // (outer +EPS on f cancels in all diffs)
  const f4 f_a = v_log(alpha + EPS_F);
  const f4 f_b = v_log(beta  + EPS_F);
  const f4 f_g = v_log(gamma + EPS_F);

  const f4 inv_den_a = v_rcp((alpha - beta) * (alpha - gamma));

  // divided difference of f over the close pair (beta,gamma), single rcp
  const f4 gap = gamma - beta;
  const f4 ga  = gamma - alpha;
  const f4 agap = v_fabs(gap);
  const f4 thr  = 1e-5f * v_max(v_fabs(beta), v_fabs(gamma));
  const f4 mid  = 0.5f * (beta + gamma) + EPS_F;
  f4 num, den;
  num.x = (agap.x > thr.x) ? (f_g.x - f_b.x) : 1.0f;
  den.x = (agap.x > thr.x) ? (gap.x * ga.x) : (mid.x * ga.x);
  num.y = (agap.y > thr.y) ? (f_g.y - f_b.y) : 1.0f;
  den.y = (agap.y > thr.y) ? (gap.y * ga.y) : (mid.y * ga.y);
  num.z = (agap.z > thr.z) ? (f_g.z - f_b.z) : 1.0f;
  den.z = (agap.z > thr.z) ? (gap.z * ga.z) : (mid.z * ga.z);
  num.w = (agap.w > thr.w) ? (f_g.w - f_b.w) : 1.0f;
  den.w = (agap.w > thr.w) ? (gap.w * ga.w) : (mid.w * ga.w);
  const f4 cg = num * v_rcp(den);
  const f4 wd = (f_a - f_b) * inv_den_a;

  // logm = c2*A^2 + c1*A + c0*I
  const f4 sbg = beta + gamma, pbg = beta * gamma;
  const f4 sab = alpha + beta, pab = alpha * beta;
  const f4 c2 = wd + cg;
  const f4 c1 = -(wd * sbg + cg * sab);
  const f4 c0 = f_b + wd * pbg + cg * pab;

  const f4 L0 = c2 * s00 + c1 * a00 + c0;
  const f4 L1 = c2 * s01 + c1 * a01;
  const f4 L2 = c2 * s02 + c1 * a02;
  const f4 L3 = c2 * s11 + c1 * a11 + c0;
  const f4 L4 = c2 * s12 + c1 * a12;
  const f4 L5 = c2 * s22 + c1 * a22 + c0;

  const float dA0 = L0.x - L0.y, dB0 = L0.z - L0.w;
  const float dA1 = L1.x - L1.y, dB1 = L1.z - L1.w;
  const float dA2 = L2.x - L2.y, dB2 = L2.z - L2.w;
  const float dA3 = L3.x - L3.y, dB3 = L3.z - L3.w;
  const float dA4 = L4.x - L4.y, dB4 = L4.z - L4.w;
  const float dA5 = L5.x - L5.y, dB5 = L5.z - L5.w;
  f2 out;
  out.x = dA0 * dA0 + dA3 * dA3 + dA5 * dA5 + 2.0f * (dA1 * dA1 + dA2 * dA2 + dA4 * dA4);
  out.y = dB0 * dB0 + dB3 * dB3 + dB5 * dB5 + 2.0f * (dB1 * dB1 + dB2 * dB2 + dB4 * dB4);
  return out;
}

// Load one item (2 consecutive matrix pairs) via 16 aligned float2 loads.
__device__ __forceinline__ void load_item(const float* __restrict__ d1,
                                          const float* __restrict__ d2, int i,
                                          f4& m00, f4& m01, f4& m02,
                                          f4& m11, f4& m12, f4& m22) {
  const float2* gA = reinterpret_cast<const float2*>(d1) + (size_t)i * 9;
  const float2* gB = reinterpret_cast<const float2*>(d2) + (size_t)i * 9;
  const float2 r0 = gA[0], r1 = gA[1], r2 = gA[2], r4 = gA[4],
               r5 = gA[5], r6 = gA[6], r7 = gA[7], r8 = gA[8];
  const float2 q0 = gB[0], q1 = gB[1], q2 = gB[2], q4 = gB[4],
               q5 = gB[5], q6 = gB[6], q7 = gB[7], q8 = gB[8];
  m00 = f4{r0.x, q0.x, r4.y, q4.y};
  m01 = f4{r0.y, q0.y, r5.x, q5.x};
  m02 = f4{r1.x, q1.x, r5.y, q5.y};
  m11 = f4{r2.x, q2.x, r6.y, q6.y};
  m12 = f4{r2.y, q2.y, r7.x, q7.x};
  m22 = f4{r4.x, q4.x, r8.y, q8.y};
}

// General (boundary) path: one item with full guards.
__device__ __forceinline__ float item_loss_guarded(const float* __restrict__ d1,
                                                   const float* __restrict__ d2,
                                                   int i, int nmat) {
  f4 m00, m01, m02, m11, m12, m22;
  const bool haveB = (2 * i + 1 < nmat);
  if (haveB) {
    load_item(d1, d2, i, m00, m01, m02, m11, m12, m22);
  } else {
    const size_t base = (size_t)(2 * i) * 9;
    m00 = f4{d1[base + 0], d2[base + 0], d1[base + 0], d2[base + 0]};
    m01 = f4{d1[base + 1], d2[base + 1], d1[base + 1], d2[base + 1]};
    m02 = f4{d1[base + 2], d2[base + 2], d1[base + 2], d2[base + 2]};
    m11 = f4{d1[base + 4], d2[base + 4], d1[base + 4], d2[base + 4]};
    m12 = f4{d1[base + 5], d2[base + 5], d1[base + 5], d2[base + 5]};
    m22 = f4{d1[base + 8], d2[base + 8], d1[base + 8], d2[base + 8]};
  }
  const f2 l = pair_loss(m00, m01, m02, m11, m12, m22);
  return l.x + (haveB ? l.y : 0.0f);
}

__global__ void __launch_bounds__(256, 4)
leloss_partial(const float* __restrict__ d1, const float* __restrict__ d2,
               float* __restrict__ partial, int nmat, int T) {
  const int nitems = (nmat + 1) >> 1;
  const int tid = threadIdx.x;
  const int t = blockIdx.x * 256 + tid;
  float acc = 0.0f;

  for (int i = t; i < nitems; i += 2 * T) {
    const int i1 = i + T;
    // fast path: both items fully in range -> straight-line, two independent chains
    if (2 * i1 + 1 < nmat) {
      f4 a00, a01, a02, a11, a12, a22;
      f4 b00, b01, b02, b11, b12, b22;
      load_item(d1, d2, i,  a00, a01, a02, a11, a12, a22);
      load_item(d1, d2, i1, b00, b01, b02, b11, b12, b22);
      const f2 l0 = pair_loss(a00, a01, a02, a11, a12, a22);
      const f2 l1 = pair_loss(b00, b01, b02, b11, b12, b22);
      acc += (l0.x + l0.y) + (l1.x + l1.y);
    } else {
      acc += item_loss_guarded(d1, d2, i, nmat);
      if (i1 < nitems) acc += item_loss_guarded(d1, d2, i1, nmat);
    }
  }

  // wave reduce (64 lanes)
#pragma unroll
  for (int off = 32; off > 0; off >>= 1) acc += __shfl_down(acc, off, 64);

  __shared__ float wsum[4];
  const int lane = tid & 63;
  const int wid  = tid >> 6;
  if (lane == 0) wsum[wid] = acc;
  __syncthreads();
  if (tid == 0) {
    partial[blockIdx.x] = wsum[0] + wsum[1] + wsum[2] + wsum[3];
  }
}

__global__ void __launch_bounds__(256)
leloss_reduce(const float* __restrict__ partial, int n,
              float* __restrict__ out, double inv_count) {
  double s = 0.0;
  for (int i = threadIdx.x; i < n; i += 256) s += (double)partial[i];
#pragma unroll
  for (int off = 32; off > 0; off >>= 1) s += __shfl_down(s, off, 64);

  __shared__ double wsum[4];
  const int lane = threadIdx.x & 63;
  const int wid  = threadIdx.x >> 6;
  if (lane == 0) wsum[wid] = s;
  __syncthreads();
  if (threadIdx.x == 0) {
    const double total = wsum[0] + wsum[1] + wsum[2] + wsum[3];
    out[0] = (float)(total * inv_count);
  }
}

extern "C" void kernel_launch(void* const* d_in, const int* in_sizes, int n_in,
                              void* d_out, int out_size, void* d_ws, size_t ws_size,
                              hipStream_t stream) {
  const float* d1 = (const float*)d_in[0];
  const float* d2 = (const float*)d_in[1];
  float* out = (float*)d_out;
  float* partial = (float*)d_ws;

  const long long nelem = (long long)in_sizes[0];
  const int nmat   = (int)(nelem / 9);
  const int nitems = (nmat + 1) >> 1;
  int nblocks = (nitems + 511) / 512;          // 2 items per thread
  if (nblocks > 2048) nblocks = 2048;
  const int T = nblocks * 256;

  leloss_partial<<<nblocks, 256, 0, stream>>>(d1, d2, partial, nmat, T);

  const double inv_count = 1.0 / ((double)nmat * 9.0);
  leloss_reduce<<<1, 256, 0, stream>>>(partial, nblocks, out, inv_count);
}

// Round 8
// 33.623 us; speedup vs baseline: 1.1278x; 1.1278x over previous
//
#include <hip/hip_runtime.h>
#include <math.h>

#define EPS_F 1e-10f

typedef __attribute__((ext_vector_type(4))) float f4;
typedef __attribute__((ext_vector_type(4))) unsigned int u4;
typedef __attribute__((ext_vector_type(2))) float f2;

__device__ __forceinline__ f4 v_fabs(f4 x) {
  u4 u = __builtin_bit_cast(u4, x);
  u &= 0x7fffffffu;
  return __builtin_bit_cast(f4, u);
}
__device__ __forceinline__ f4 v_max(f4 a, f4 b) { return __builtin_elementwise_max(a, b); }
__device__ __forceinline__ f4 v_min(f4 a, f4 b) { return __builtin_elementwise_min(a, b); }
__device__ __forceinline__ f4 v_log(f4 x) {
  f4 r; r.x = __logf(x.x); r.y = __logf(x.y); r.z = __logf(x.z); r.w = __logf(x.w); return r;
}
__device__ __forceinline__ f4 v_rcp(f4 x) {
  f4 r;
  r.x = __builtin_amdgcn_rcpf(x.x); r.y = __builtin_amdgcn_rcpf(x.y);
  r.z = __builtin_amdgcn_rcpf(x.z); r.w = __builtin_amdgcn_rcpf(x.w);
  return r;
}
__device__ __forceinline__ f4 v_rsq(f4 x) {
  f4 r;
  r.x = __builtin_amdgcn_rsqf(x.x); r.y = __builtin_amdgcn_rsqf(x.y);
  r.z = __builtin_amdgcn_rsqf(x.z); r.w = __builtin_amdgcn_rsqf(x.w);
  return r;
}
__device__ __forceinline__ f4 v_sqrt(f4 x) {
  f4 r;
  r.x = __builtin_amdgcn_sqrtf(x.x); r.y = __builtin_amdgcn_sqrtf(x.y);
  r.z = __builtin_amdgcn_sqrtf(x.z); r.w = __builtin_amdgcn_sqrtf(x.w);
  return r;
}
__device__ __forceinline__ f4 v_cos(f4 x) {
  f4 r; r.x = __cosf(x.x); r.y = __cosf(x.y); r.z = __cosf(x.z); r.w = __cosf(x.w); return r;
}

// acos via minimax poly (|err| ~ 2e-8 rad)
__device__ __forceinline__ f4 v_acos(f4 r) {
  const f4 t = v_fabs(r);
  const f4 s = v_sqrt(1.0f - t);
  f4 p = f4{-0.0012624911f, -0.0012624911f, -0.0012624911f, -0.0012624911f};
  p = p * t +  0.0066700901f;
  p = p * t + -0.0170881256f;
  p = p * t +  0.0308918810f;
  p = p * t + -0.0501743046f;
  p = p * t +  0.0889789874f;
  p = p * t + -0.2145988016f;
  p = p * t +  1.5707963050f;
  const f4 ac = s * p;                         // acos(|r|)
  f4 res;
  res.x = (r.x < 0.0f) ? (3.14159265358979f - ac.x) : ac.x;
  res.y = (r.y < 0.0f) ? (3.14159265358979f - ac.y) : ac.y;
  res.z = (r.z < 0.0f) ? (3.14159265358979f - ac.z) : ac.z;
  res.w = (r.w < 0.0f) ? (3.14159265358979f - ac.w) : ac.w;
  return res;
}

// Fused ||logm(D1)-logm(D2)||_F^2 for TWO matrix pairs in lockstep:
// lanes = {D1_pairA, D2_pairA, D1_pairB, D2_pairB}. Returns lossA + lossB.
__device__ __forceinline__ float pair_loss(f4 a00, f4 a01, f4 a02,
                                           f4 a11, f4 a12, f4 a22) {
  a00 = v_fabs(a00); a01 = v_fabs(a01); a02 = v_fabs(a02);
  a11 = v_fabs(a11); a12 = v_fabs(a12); a22 = v_fabs(a22);

  const f4 q   = (a00 + a11 + a22) * (1.0f / 3.0f);
  const f4 b00 = a00 - q, b11 = a11 - q, b22 = a22 - q;
  const f4 p2  = b00 * b00 + b11 * b11 + b22 * b22 +
                 2.0f * (a01 * a01 + a02 * a02 + a12 * a12);

  // p2c = max(p2/6, floor) keeps p>0 so downstream denominators stay normal
  const f4 p2c  = v_max(p2 * (1.0f / 6.0f), 1e-10f * q * q + 1e-35f);
  const f4 pinv = v_rsq(p2c);          // 1/p
  const f4 p    = p2c * pinv;          // sqrt(p2c)

  const f4 detB = b00 * (b11 * b22 - a12 * a12)
                - a01 * (a01 * b22 - a12 * a02)
                + a02 * (a01 * a12 - b11 * a02);
  f4 r = detB * 0.5f * pinv * pinv * pinv;
  r = v_min(f4{1.0f, 1.0f, 1.0f, 1.0f}, v_max(f4{-1.0f, -1.0f, -1.0f, -1.0f}, r));
  const f4 phi  = v_acos(r) * (1.0f / 3.0f);
  const f4 twop = 2.0f * p;
  const f4 l1 = q + twop * v_cos(phi);                          // largest
  const f4 l3 = q + twop * v_cos(phi + 2.0943951023931953f);    // smallest
  const f4 l2 = 3.0f * q - l1 - l3;

  // A^2 (symmetric, unique entries)
  const f4 s00 = a00 * a00 + a01 * a01 + a02 * a02;
  const f4 s01 = a00 * a01 + a01 * a11 + a02 * a12;
  const f4 s02 = a00 * a02 + a01 * a12 + a02 * a22;
  const f4 s11 = a01 * a01 + a11 * a11 + a12 * a12;
  const f4 s12 = a01 * a02 + a11 * a12 + a12 * a22;
  const f4 s22 = a02 * a02 + a12 * a12 + a22 * a22;

  // isolated extreme eigenvalue = alpha; beta = middle; gamma = other extreme
  const f4 g12 = l1 - l2, g23 = l2 - l3;
  f4 alpha, gamma;
  alpha.x = (g12.x >= g23.x) ? l1.x : l3.x;  gamma.x = (g12.x >= g23.x) ? l3.x : l1.x;
  alpha.y = (g12.y >= g23.y) ? l1.y : l3.y;  gamma.y = (g12.y >= g23.y) ? l3.y : l1.y;
  alpha.z = (g12.z >= g23.z) ? l1.z : l3.z;  gamma.z = (g12.z >= g23.z) ? l3.z : l1.z;
  alpha.w = (g12.w >= g23.w) ? l1.w : l3.w;  gamma.w = (g12.w >= g23.w) ? l3.w : l1.w;
  const f4 beta = l2;

  // (outer +EPS on f cancels in all diffs)
  const f4 f_a = v_log(alpha + EPS_F);
  const f4 f_b = v_log(beta  + EPS_F);
  const f4 f_g = v_log(gamma + EPS_F);

  const f4 inv_den_a = v_rcp((alpha - beta) * (alpha - gamma));

  // divided difference of f over the close pair (beta,gamma), single rcp
  const f4 gap = gamma - beta;
  const f4 ga  = gamma - alpha;
  const f4 agap = v_fabs(gap);
  const f4 thr  = 1e-5f * v_max(v_fabs(beta), v_fabs(gamma));
  const f4 mid  = 0.5f * (beta + gamma) + EPS_F;
  f4 num, den;
  num.x = (agap.x > thr.x) ? (f_g.x - f_b.x) : 1.0f;
  den.x = (agap.x > thr.x) ? (gap.x * ga.x) : (mid.x * ga.x);
  num.y = (agap.y > thr.y) ? (f_g.y - f_b.y) : 1.0f;
  den.y = (agap.y > thr.y) ? (gap.y * ga.y) : (mid.y * ga.y);
  num.z = (agap.z > thr.z) ? (f_g.z - f_b.z) : 1.0f;
  den.z = (agap.z > thr.z) ? (gap.z * ga.z) : (mid.z * ga.z);
  num.w = (agap.w > thr.w) ? (f_g.w - f_b.w) : 1.0f;
  den.w = (agap.w > thr.w) ? (gap.w * ga.w) : (mid.w * ga.w);
  const f4 cg = num * v_rcp(den);
  const f4 wd = (f_a - f_b) * inv_den_a;

  // logm = c2*A^2 + c1*A + c0*I
  const f4 sbg = beta + gamma, pbg = beta * gamma;
  const f4 sab = alpha + beta, pab = alpha * beta;
  const f4 c2 = wd + cg;
  const f4 c1 = -(wd * sbg + cg * sab);
  const f4 c0 = f_b + wd * pbg + cg * pab;

  const f4 L0 = c2 * s00 + c1 * a00 + c0;
  const f4 L1 = c2 * s01 + c1 * a01;
  const f4 L2 = c2 * s02 + c1 * a02;
  const f4 L3 = c2 * s11 + c1 * a11 + c0;
  const f4 L4 = c2 * s12 + c1 * a12;
  const f4 L5 = c2 * s22 + c1 * a22 + c0;

  const float dA0 = L0.x - L0.y, dB0 = L0.z - L0.w;
  const float dA1 = L1.x - L1.y, dB1 = L1.z - L1.w;
  const float dA2 = L2.x - L2.y, dB2 = L2.z - L2.w;
  const float dA3 = L3.x - L3.y, dB3 = L3.z - L3.w;
  const float dA4 = L4.x - L4.y, dB4 = L4.z - L4.w;
  const float dA5 = L5.x - L5.y, dB5 = L5.z - L5.w;
  return dA0 * dA0 + dA3 * dA3 + dA5 * dA5 + 2.0f * (dA1 * dA1 + dA2 * dA2 + dA4 * dA4)
       + dB0 * dB0 + dB3 * dB3 + dB5 * dB5 + 2.0f * (dB1 * dB1 + dB2 * dB2 + dB4 * dB4);
}

// Each work-item = 2 consecutive matrix pairs (18 floats per tensor = 8 used
// aligned float2 loads per tensor). Exactly ONE item per thread.
__global__ void __launch_bounds__(256, 4)
leloss_partial(const float* __restrict__ d1, const float* __restrict__ d2,
               float* __restrict__ partial, int nitems) {
  const int tid = threadIdx.x;
  const int i = blockIdx.x * 256 + tid;
  float acc = 0.0f;

  if (i < nitems) {
    const float2* gA = reinterpret_cast<const float2*>(d1) + (size_t)i * 9;
    const float2* gB = reinterpret_cast<const float2*>(d2) + (size_t)i * 9;
    const float2 r0 = gA[0], r1 = gA[1], r2 = gA[2], r4 = gA[4],
                 r5 = gA[5], r6 = gA[6], r7 = gA[7], r8 = gA[8];
    const float2 q0 = gB[0], q1 = gB[1], q2 = gB[2], q4 = gB[4],
                 q5 = gB[5], q6 = gB[6], q7 = gB[7], q8 = gB[8];
    const f4 m00 = f4{r0.x, q0.x, r4.y, q4.y};
    const f4 m01 = f4{r0.y, q0.y, r5.x, q5.x};
    const f4 m02 = f4{r1.x, q1.x, r5.y, q5.y};
    const f4 m11 = f4{r2.x, q2.x, r6.y, q6.y};
    const f4 m12 = f4{r2.y, q2.y, r7.x, q7.x};
    const f4 m22 = f4{r4.x, q4.x, r8.y, q8.y};
    acc = pair_loss(m00, m01, m02, m11, m12, m22);
  }

  // wave reduce (64 lanes)
#pragma unroll
  for (int off = 32; off > 0; off >>= 1) acc += __shfl_down(acc, off, 64);

  __shared__ float wsum[4];
  const int lane = tid & 63;
  const int wid  = tid >> 6;
  if (lane == 0) wsum[wid] = acc;
  __syncthreads();
  if (tid == 0) {
    partial[blockIdx.x] = wsum[0] + wsum[1] + wsum[2] + wsum[3];
  }
}

// Handles the last (possibly odd) matrix if nmat is odd: adds its loss into
// partial[0] is avoided; instead we give it to a dedicated extra partial slot.
__global__ void leloss_tail(const float* __restrict__ d1, const float* __restrict__ d2,
                            float* __restrict__ partial_slot, int mat_idx) {
  const size_t base = (size_t)mat_idx * 9;
  const f4 m00 = f4{d1[base + 0], d2[base + 0], d1[base + 0], d2[base + 0]};
  const f4 m01 = f4{d1[base + 1], d2[base + 1], d1[base + 1], d2[base + 1]};
  const f4 m02 = f4{d1[base + 2], d2[base + 2], d1[base + 2], d2[base + 2]};
  const f4 m11 = f4{d1[base + 4], d2[base + 4], d1[base + 4], d2[base + 4]};
  const f4 m12 = f4{d1[base + 5], d2[base + 5], d1[base + 5], d2[base + 5]};
  const f4 m22 = f4{d1[base + 8], d2[base + 8], d1[base + 8], d2[base + 8]};
  // duplicated into both item slots -> halve
  partial_slot[0] = 0.5f * pair_loss(m00, m01, m02, m11, m12, m22);
}

__global__ void __launch_bounds__(256)
leloss_reduce(const float* __restrict__ partial, int n,
              float* __restrict__ out, double inv_count) {
  double s = 0.0;
  for (int i = threadIdx.x; i < n; i += 256) s += (double)partial[i];
#pragma unroll
  for (int off = 32; off > 0; off >>= 1) s += __shfl_down(s, off, 64);

  __shared__ double wsum[4];
  const int lane = threadIdx.x & 63;
  const int wid  = threadIdx.x >> 6;
  if (lane == 0) wsum[wid] = s;
  __syncthreads();
  if (threadIdx.x == 0) {
    const double total = wsum[0] + wsum[1] + wsum[2] + wsum[3];
    out[0] = (float)(total * inv_count);
  }
}

extern "C" void kernel_launch(void* const* d_in, const int* in_sizes, int n_in,
                              void* d_out, int out_size, void* d_ws, size_t ws_size,
                              hipStream_t stream) {
  const float* d1 = (const float*)d_in[0];
  const float* d2 = (const float*)d_in[1];
  float* out = (float*)d_out;
  float* partial = (float*)d_ws;

  const long long nelem = (long long)in_sizes[0];
  const int nmat   = (int)(nelem / 9);
  const int nitems = nmat >> 1;                 // full 2-pair items
  const int nblocks = (nitems + 255) / 256;     // one item per thread

  leloss_partial<<<nblocks, 256, 0, stream>>>(d1, d2, partial, nitems);

  int npart = nblocks;
  if (nmat & 1) {                               // odd tail matrix (not for this size)
    leloss_tail<<<1, 1, 0, stream>>>(d1, d2, partial + npart, nmat - 1);
    ++npart;
  }

  const double inv_count = 1.0 / ((double)nmat * 9.0);
  leloss_reduce<<<1, 256, 0, stream>>>(partial, npart, out, inv_count);
}